// Round 1
// baseline (305.450 us; speedup 1.0000x reference)
//
#include <hip/hip_runtime.h>
#include <stdint.h>

#define BB 4
#define CC 256
#define NN 4096   // H*W = 64*64

typedef __attribute__((ext_vector_type(8))) short short8;
typedef __attribute__((ext_vector_type(4))) float floatx4;
typedef __attribute__((ext_vector_type(4))) unsigned int uint4v;

__device__ __forceinline__ unsigned short f2bf(float f) {
    unsigned int u = __builtin_bit_cast(unsigned int, f);
    u = (u + 0x7FFFu + ((u >> 16) & 1u)) >> 16;   // RNE
    return (unsigned short)u;
}

__device__ __forceinline__ floatx4 mfma16(short8 a, short8 b, floatx4 c) {
    return __builtin_amdgcn_mfma_f32_16x16x32_bf16(a, b, c, 0, 0, 0);
}

// ---------------------------------------------------------------------------
// k_norm: inv_norm[b][n] = 1 / max(sqrt(sum_c x[b,c,n]^2), 1e-8)
// grid 256 blocks x 256 thr; block = (b, 64-n chunk); 4 partial sums per n.
// ---------------------------------------------------------------------------
__global__ __launch_bounds__(256) void k_norm(const float* __restrict__ x,
                                              float* __restrict__ invn) {
    int blk = blockIdx.x;          // b*64 + nchunk
    int b  = blk >> 6;
    int n0 = (blk & 63) << 6;
    int t  = threadIdx.x;
    int n  = n0 + (t & 63);
    int cg = t >> 6;               // 0..3
    const float* xp = x + (size_t)(b * CC + cg * 64) * NN + n;
    float ss = 0.f;
    #pragma unroll 8
    for (int c = 0; c < 64; ++c) {
        float v = xp[(size_t)c * NN];
        ss = fmaf(v, v, ss);
    }
    __shared__ float red[256];
    red[t] = ss;
    __syncthreads();
    if (t < 64) {
        float s = red[t] + red[t + 64] + red[t + 128] + red[t + 192];
        float nrm = fmaxf(sqrtf(s), 1e-8f);
        invn[b * NN + n0 + t] = 1.f / nrm;
    }
}

// ---------------------------------------------------------------------------
// k_trans: xT[b][n][c] = bf16(x[b][c][n])   (64x64 LDS tile transpose)
// grid 1024 blocks (b*4cc*64nc) x 256 thr
// ---------------------------------------------------------------------------
__global__ __launch_bounds__(256) void k_trans(const float* __restrict__ x,
                                               unsigned short* __restrict__ xT) {
    int blk = blockIdx.x;
    int b  = blk >> 8;
    int cc = (blk >> 6) & 3;
    int nc = blk & 63;
    int c0 = cc << 6, n0 = nc << 6;
    __shared__ float tile[64][65];     // +1 pad: conflict-free column reads
    int t = threadIdx.x;
    {
        int c   = t >> 2;
        int nn4 = (t & 3) << 4;
        const float* src = x + (size_t)(b * CC + c0 + c) * NN + n0 + nn4;
        #pragma unroll
        for (int j = 0; j < 16; j += 4) {
            floatx4 v = *(const floatx4*)(src + j);
            tile[c][nn4 + j + 0] = v[0];
            tile[c][nn4 + j + 1] = v[1];
            tile[c][nn4 + j + 2] = v[2];
            tile[c][nn4 + j + 3] = v[3];
        }
    }
    __syncthreads();
    int n  = t >> 2;
    int ci = (t & 3) << 4;
    unsigned short* dst = xT + (size_t)(b * NN + n0 + n) * CC + c0 + ci;
    unsigned int w[8];
    #pragma unroll
    for (int j = 0; j < 8; ++j) {
        unsigned int lo = f2bf(tile[ci + 2 * j][n]);
        unsigned int hi = f2bf(tile[ci + 2 * j + 1][n]);
        w[j] = lo | (hi << 16);
    }
    uint4v w0 = {w[0], w[1], w[2], w[3]};
    uint4v w1 = {w[4], w[5], w[6], w[7]};
    *(uint4v*)(dst)     = w0;
    *(uint4v*)(dst + 8) = w1;
}

// ---------------------------------------------------------------------------
// k_conv: tf[b][o][n] = bf16( sum_c W[o][c]*x[b][c][n] + bias[o] )
// MFMA 16x16x32 bf16. grid 1024 (b*4ot*64nt) x 256 thr (4 waves).
// Wave w: o rows [o0+16w, +16), 4 n-subtiles. A = W (cast inline), B = xT rows.
// ---------------------------------------------------------------------------
__global__ __launch_bounds__(256) void k_conv(const float* __restrict__ Wm,
                                              const float* __restrict__ bias,
                                              const unsigned short* __restrict__ xT,
                                              unsigned short* __restrict__ tf) {
    int blk = blockIdx.x;
    int b  = blk >> 8;
    int ot = (blk >> 6) & 3;
    int nt = blk & 63;
    int o0 = ot << 6, n0 = nt << 6;
    int t = threadIdx.x;
    int w = t >> 6, l = t & 63, l15 = l & 15, q = l >> 4;
    int orow = o0 + 16 * w + l15;

    floatx4 zero4 = {0.f, 0.f, 0.f, 0.f};
    floatx4 acc[4] = {zero4, zero4, zero4, zero4};
    const float* wp0 = Wm + (size_t)orow * CC + q * 8;

    #pragma unroll
    for (int kk = 0; kk < 8; ++kk) {
        const float* wp = wp0 + kk * 32;
        floatx4 wa = *(const floatx4*)wp;
        floatx4 wb = *(const floatx4*)(wp + 4);
        short8 af;
        #pragma unroll
        for (int j = 0; j < 4; ++j) {
            af[j]     = (short)f2bf(wa[j]);
            af[4 + j] = (short)f2bf(wb[j]);
        }
        #pragma unroll
        for (int s = 0; s < 4; ++s) {
            const unsigned short* bp =
                xT + (size_t)(b * NN + n0 + 16 * s + l15) * CC + kk * 32 + q * 8;
            short8 bf = *(const short8*)bp;
            acc[s] = mfma16(af, bf, acc[s]);
        }
    }
    int obase = o0 + 16 * w + q * 4;    // D rows = quad*4 + i
    float bv0 = bias[obase + 0], bv1 = bias[obase + 1];
    float bv2 = bias[obase + 2], bv3 = bias[obase + 3];
    #pragma unroll
    for (int s = 0; s < 4; ++s) {
        int n = n0 + 16 * s + l15;      // D col = lane&15
        tf[(size_t)(b * CC + obase + 0) * NN + n] = f2bf(acc[s][0] + bv0);
        tf[(size_t)(b * CC + obase + 1) * NN + n] = f2bf(acc[s][1] + bv1);
        tf[(size_t)(b * CC + obase + 2) * NN + n] = f2bf(acc[s][2] + bv2);
        tf[(size_t)(b * CC + obase + 3) * NN + n] = f2bf(acc[s][3] + bv3);
    }
}

// ---------------------------------------------------------------------------
// k_fused: flash-style. Block = (b, 64 queries). 512 thr = 8 waves.
// Loop over 64-key tiles:  S = Xq^T Xm (K=256), P = relu(S*invq*invm)^2 -> LDS,
// O[c][nq] += tf * P  (tf = A operand from global, P = B operand from LDS).
// Wave (wv): S: mk-subtile ms=wv&3, nq-subtiles {na,na+1}, na=2*(wv>>2).
//            2nd GEMM: c-tiles 4*cg..+3 (cg=wv&3), same nq-subtiles.
// ---------------------------------------------------------------------------
__global__ __launch_bounds__(512, 2) void k_fused(
        const unsigned short* __restrict__ xT,   // [B][N][C] bf16
        const unsigned short* __restrict__ tf,   // [B][C][N] bf16
        const float* __restrict__ invn,          // [B][N]
        float* __restrict__ out) {               // [B][C][N] f32
    int blk = blockIdx.x;           // b*64 + qtile
    int b  = blk >> 6;
    int n0 = (blk & 63) << 6;
    int t  = threadIdx.x;
    int wv = t >> 6;
    int l = t & 63, l15 = l & 15, q = l >> 4;
    int ms = wv & 3;
    int na = (wv >> 2) << 1;        // 0 or 2
    int cg = wv & 3;

    __shared__ unsigned short xm[64 * 264];        // [64 keys][264] (512B+16B pad)
    __shared__ unsigned short pbuf[4][16 * 72];    // per nq-subtile [16][72] (128B+16B pad)

    const unsigned short* xTb = xT + (size_t)b * NN * CC;
    const unsigned short* tfb = tf + (size_t)b * CC * NN;
    const float* invb = invn + b * NN;

    // Xq A-fragments (persist all kernel): A[m=lane&15][k=quad*8+j]
    short8 aq[2][8];
    #pragma unroll
    for (int s = 0; s < 2; ++s) {
        const unsigned short* p = xTb + (size_t)(n0 + 16 * (na + s) + l15) * CC + q * 8;
        #pragma unroll
        for (int kk = 0; kk < 8; ++kk) aq[s][kk] = *(const short8*)(p + kk * 32);
    }
    // inverse norms for this wave's D rows (row = quad*4+i)
    float invq[2][4];
    #pragma unroll
    for (int s = 0; s < 2; ++s)
        #pragma unroll
        for (int i = 0; i < 4; ++i)
            invq[s][i] = invb[n0 + 16 * (na + s) + q * 4 + i];

    floatx4 zero4 = {0.f, 0.f, 0.f, 0.f};
    floatx4 oacc[2][4];
    #pragma unroll
    for (int s = 0; s < 2; ++s)
        #pragma unroll
        for (int ct = 0; ct < 4; ++ct) oacc[s][ct] = zero4;

    // xm staging map: lane row = t&63, 64B segment = t>>6 (conflict-free writes)
    int srow = t & 63;
    int sseg = (t >> 6) * 32;       // shorts
    unsigned short* ldst = &xm[srow * 264 + sseg];

    uint4v gx[4];
    {
        const unsigned short* gs = xTb + (size_t)srow * CC + sseg;   // tile 0
        #pragma unroll
        for (int j = 0; j < 4; ++j) gx[j] = *(const uint4v*)(gs + j * 8);
    }

    for (int it = 0; it < 64; ++it) {
        int m0 = it * 64;
        __syncthreads();                              // xm free (prev readers done)
        #pragma unroll
        for (int j = 0; j < 4; ++j) *(uint4v*)(ldst + j * 8) = gx[j];
        __syncthreads();                              // xm visible

        // prefetch next key tile (drains at next barrier -> overlapped w/ S-phase)
        if (it < 63) {
            const unsigned short* gs = xTb + (size_t)((it + 1) * 64 + srow) * CC + sseg;
            #pragma unroll
            for (int j = 0; j < 4; ++j) gx[j] = *(const uint4v*)(gs + j * 8);
        }
        // prefetch tf A-fragments for this tile: A[m=c][k=mk]
        short8 tfr[2][4];
        #pragma unroll
        for (int kk2 = 0; kk2 < 2; ++kk2)
            #pragma unroll
            for (int ct = 0; ct < 4; ++ct) {
                int c = 16 * (4 * cg + ct) + l15;
                tfr[kk2][ct] = *(const short8*)(tfb + (size_t)c * NN + m0 + kk2 * 32 + q * 8);
            }
        float invm = invb[m0 + 16 * ms + l15];        // D col = lane&15

        // ---- S phase: S[nq][mk] = sum_c x[c][nq]x[c][mk], parity-split accs ----
        floatx4 sa0 = zero4, sa1 = zero4, sb0 = zero4, sb1 = zero4;
        const unsigned short* bbase = &xm[(16 * ms + l15) * 264 + q * 8];
        #pragma unroll
        for (int kk = 0; kk < 8; kk += 2) {
            short8 b0 = *(const short8*)(bbase + kk * 32);
            short8 b1 = *(const short8*)(bbase + kk * 32 + 32);
            sa0 = mfma16(aq[0][kk], b0, sa0);
            sa1 = mfma16(aq[1][kk], b0, sa1);
            sb0 = mfma16(aq[0][kk + 1], b1, sb0);
            sb1 = mfma16(aq[1][kk + 1], b1, sb1);
        }
        // ---- P = relu(S*invq*invm)^2 -> bf16 -> LDS (A-layout source) ----
        #pragma unroll
        for (int s = 0; s < 2; ++s) {
            floatx4 sv = (s == 0) ? (sa0 + sb0) : (sa1 + sb1);
            unsigned short* pw = &pbuf[na + s][16 * ms + l15];
            #pragma unroll
            for (int i = 0; i < 4; ++i) {
                float v = sv[i] * (invq[s][i] * invm);
                v = fmaxf(v, 0.f);
                v = v * v;
                pw[(q * 4 + i) * 72] = f2bf(v);
            }
        }
        __syncthreads();                              // P visible

        // ---- O[c][nq] += tf * P : A=tfr (m=c), B=P (n=nq) ----
        #pragma unroll
        for (int kk2 = 0; kk2 < 2; ++kk2) {
            short8 pb0 = *(const short8*)(&pbuf[na + 0][l15 * 72 + kk2 * 32 + q * 8]);
            short8 pb1 = *(const short8*)(&pbuf[na + 1][l15 * 72 + kk2 * 32 + q * 8]);
            #pragma unroll
            for (int ct = 0; ct < 4; ++ct) {
                oacc[0][ct] = mfma16(tfr[kk2][ct], pb0, oacc[0][ct]);
                oacc[1][ct] = mfma16(tfr[kk2][ct], pb1, oacc[1][ct]);
            }
        }
    }

    // epilogue: D row = c (quad*4+i), D col = nq (lane&15) -> coalesced stores
    float* ob = out + (size_t)b * CC * NN;
    #pragma unroll
    for (int s = 0; s < 2; ++s)
        #pragma unroll
        for (int ct = 0; ct < 4; ++ct)
            #pragma unroll
            for (int i = 0; i < 4; ++i) {
                int c = 16 * (4 * cg + ct) + q * 4 + i;
                ob[(size_t)c * NN + n0 + 16 * (na + s) + l15] = oacc[s][ct][i];
            }
}

// ---------------------------------------------------------------------------
extern "C" void kernel_launch(void* const* d_in, const int* in_sizes, int n_in,
                              void* d_out, int out_size, void* d_ws, size_t ws_size,
                              hipStream_t stream) {
    const float* x    = (const float*)d_in[0];   // [4,256,64,64]
    const float* Wm   = (const float*)d_in[1];   // [256,256]
    const float* bias = (const float*)d_in[2];   // [256]
    float* out = (float*)d_out;

    // workspace: invn (64KB) | xT bf16 (8MB) | tf bf16 (8MB)  => 16.9MB total
    char* ws = (char*)d_ws;
    float* invn        = (float*)ws;
    unsigned short* xT = (unsigned short*)(ws + 65536);
    unsigned short* tf = (unsigned short*)(ws + 65536 + 8388608);

    k_norm <<<256,  256, 0, stream>>>(x, invn);
    k_trans<<<1024, 256, 0, stream>>>(x, xT);
    k_conv <<<1024, 256, 0, stream>>>(Wm, bias, xT, tf);
    k_fused<<<256,  512, 0, stream>>>(xT, tf, invn, out);
}